// Round 14
// baseline (154.158 us; speedup 1.0000x reference)
//
#include <hip/hip_runtime.h>
#include <hip/hip_fp16.h>
#include <math.h>

// Problem dims
#define BB 8
#define SS 32
#define NN 512
#define FIN 24
#define CC 56
#define EBN 262144
#define ESN 8192
#define EDD 4
#define NG (SS*NN)   // 16384 nodes per sample in bend graph
#define BCAP 128     // bucket capacity (avg deg 16, Poisson-tail max ~45)
#define SCAP 128
#define HROW (CC*2)  // h row bytes (fp16)

// ---------------- small helpers ----------------
__device__ __forceinline__ float wave_sum(float v) {
    #pragma unroll
    for (int o = 32; o > 0; o >>= 1) v += __shfl_xor(v, o);
    return v;
}

// ---------------- K0: prep params + zero bucket counts ----------------
// P layout: [0..3]=u_bend, [4]=c_bend, [5..8]=u_sec, [9]=c_sec, [10]=w0, [11]=w1
//           [16..39]=wa_src_b, [40..63]=wa_dst_b, [64..87]=wa_src_s, [88..111]=wa_dst_s
__global__ void k0_init(const float* enc_W, const float* enc_b,
                        const float* Wb, const float* a_src_b, const float* a_dst_b,
                        const float* We_b, const float* a_e_b,
                        const float* Ws, const float* a_src_s, const float* a_dst_s,
                        const float* We_s, const float* a_e_s,
                        const float* mix_w, float* P, int* cnts) {
    int i = blockIdx.x * blockDim.x + threadIdx.x;
    if (i < NG + NN) cnts[i] = 0;          // bcnt | scnt contiguous
    if (blockIdx.x == 0) {
        int t = threadIdx.x;
        if (t < 96) {
            // fold W @ a vectors: P[16 + v*24 + f] = sum_c W[f][c] * a[c]
            int v = t / FIN, f = t % FIN;
            const float* W = (v < 2) ? Wb : Ws;
            const float* a = (v == 0) ? a_src_b : (v == 1) ? a_dst_b
                           : (v == 2) ? a_src_s : a_dst_s;
            float d = 0.f;
            for (int c = 0; c < CC; ++c) d = fmaf(W[f*CC + c], a[c], d);
            P[16 + t] = d;
        }
        if (t == 0) {
            float tb[EDD], ts[EDD];
            for (int j = 0; j < EDD; ++j) {
                float vb = 0.f, vs = 0.f;
                for (int c = 0; c < CC; ++c) {
                    vb += We_b[j*CC + c] * a_e_b[c];
                    vs += We_s[j*CC + c] * a_e_s[c];
                }
                tb[j] = vb; ts[j] = vs;
            }
            float cb = 0.f, cs = 0.f;
            for (int j = 0; j < EDD; ++j) { cb += enc_b[j]*tb[j]; cs += enc_b[j]*ts[j]; }
            for (int d = 0; d < EDD; ++d) {
                float ub = 0.f, us = 0.f;
                for (int j = 0; j < EDD; ++j) {
                    ub += enc_W[d*EDD + j] * tb[j];
                    us += enc_W[d*EDD + j] * ts[j];
                }
                P[d] = ub; P[5 + d] = us;
            }
            P[4] = cb; P[9] = cs;
            float m0 = mix_w[0], m1 = mix_w[1];
            float mm = fmaxf(m0, m1);
            float e0 = expf(m0 - mm), e1 = expf(m1 - mm);
            float inv = 1.f / (e0 + e1);
            P[10] = e0 * inv; P[11] = e1 * inv;
        }
    }
}

// ---------------- K1: feat (LDS-staged) + fill(src+eid) + edge-order elog --------
#define FNB 64                          // nodes per feat block
#define FEAT_NB (BB*NG/FNB)             // 2048 blocks; 16 nodes/wave
#define FILLB_NB ((EBN+255)/256)        // 1024
#define FILLS_NB ((ESN+255)/256)        // 32
#define ELOG_NB ((BB*(EBN+ESN)+255)/256) // 8448

__global__ __launch_bounds__(256, 4) void k1_all(
        const float* __restrict__ x,
        const int* __restrict__ bend_ei, const int* __restrict__ sec_ei,
        const float* __restrict__ bend_attr, const float* __restrict__ sec_attr,
        const float* __restrict__ Wb, const float* __restrict__ Ws,
        const float* __restrict__ P,
        unsigned short* __restrict__ h_b, unsigned short* __restrict__ h_s,
        float* __restrict__ asb, float* __restrict__ adb,
        float* __restrict__ ass, float* __restrict__ ads,
        float* __restrict__ elog_b, float* __restrict__ elog_s,
        int* __restrict__ bcnt, int* __restrict__ bbuck, int* __restrict__ bbeid,
        int* __restrict__ scnt, int* __restrict__ sbuck, int* __restrict__ sbeid) {
    __shared__ float xs[FNB * FIN];     // 6 KB x slab (feat branch only)
    int blk = blockIdx.x;
    int t = threadIdx.x;
    if (blk < FEAT_NB) {
        // ---- node features: stage x slab, then one matrix per pass (wc[24] live)
        const float4* xg = (const float4*)(x + (size_t)blk * FNB * FIN);
        float4* xs4 = (float4*)xs;
        #pragma unroll
        for (int i = 0; i < (FNB*FIN/4 + 255) / 256; ++i) {
            int idx = t + i * 256;
            if (idx < FNB*FIN/4) xs4[idx] = xg[idx];
        }
        int w = t >> 6, lane = t & 63;
        int nl0 = w * (FNB / 4);            // 16 nodes per wave
        __syncthreads();
        #pragma unroll 1
        for (int m = 0; m < 2; ++m) {
            const float* W = m ? Ws : Wb;
            unsigned short* h = m ? h_s : h_b;
            float* asx = m ? ass : asb;
            float* adx = m ? ads : adb;
            // pseudo-channels: lane 56 -> alpha_src, lane 57 -> alpha_dst (folded W@a)
            float wc[FIN];
            #pragma unroll
            for (int f = 0; f < FIN; ++f) {
                float v = 0.f;
                if (lane < CC) v = W[f*CC + lane];
                else if (lane < 58) v = P[16 + m*48 + (lane - 56)*FIN + f];
                wc[f] = v;
            }
            #pragma unroll 2
            for (int n0 = 0; n0 < FNB / 4; ++n0) {
                int nl = nl0 + n0;
                size_t node = (size_t)blk * FNB + nl;
                const float4* xr = (const float4*)(xs + nl * FIN);
                float acc = 0.f;
                #pragma unroll
                for (int q = 0; q < FIN/4; ++q) {
                    float4 v = xr[q];           // broadcast ds_read_b128
                    acc = fmaf(v.x, wc[4*q+0], acc);
                    acc = fmaf(v.y, wc[4*q+1], acc);
                    acc = fmaf(v.z, wc[4*q+2], acc);
                    acc = fmaf(v.w, wc[4*q+3], acc);
                }
                if (lane < CC) h[node*CC + lane] = __half_as_ushort(__float2half(acc));
                else if (lane == 56) asx[node] = acc;
                else if (lane == 57) adx[node] = acc;
            }
        }
    } else if (blk < FEAT_NB + FILLB_NB) {
        // ---- bend bucket fill: src + eid per slot (4B scatters)
        int i = (blk - FEAT_NB) * 256 + t;
        if (i < EBN) {
            int s = bend_ei[i];
            int d = bend_ei[EBN + i];
            int p = atomicAdd(&bcnt[d], 1);
            if (p < BCAP) {
                bbuck[d * BCAP + p] = s;
                bbeid[d * BCAP + p] = i;
            }
        }
    } else if (blk < FEAT_NB + FILLB_NB + FILLS_NB) {
        // ---- section bucket fill
        int i = (blk - FEAT_NB - FILLB_NB) * 256 + t;
        if (i < ESN) {
            int s = sec_ei[i];
            int d = sec_ei[ESN + i];
            int p = atomicAdd(&scnt[d], 1);
            if (p < SCAP) {
                sbuck[d * SCAP + p] = s;
                sbeid[d * SCAP + p] = i;
            }
        }
    } else {
        // ---- per-edge scalar logit terms, edge order (fully coalesced)
        int i = (blk - FEAT_NB - FILLB_NB - FILLS_NB) * 256 + t;
        const int nb = BB * EBN;
        if (i < nb) {
            float4 a = ((const float4*)bend_attr)[i];
            elog_b[i] = fmaf(a.x, P[0], fmaf(a.y, P[1], fmaf(a.z, P[2], fmaf(a.w, P[3], P[4]))));
        } else if (i < nb + BB * ESN) {
            int j = i - nb;
            float4 a = ((const float4*)sec_attr)[j];
            elog_s[j] = fmaf(a.x, P[5], fmaf(a.y, P[6], fmaf(a.z, P[7], fmaf(a.w, P[8], P[9]))));
        }
    }
}

// ---------------- KT: transpose elog (edge order) -> CSR slot order ----------------
// Random reads are 4B within a 1 MB per-batch slab (L2-resident); writes coalesced.
#define TSB_NB ((NG*BCAP + 255)/256)    // 8192
#define TSS_NB ((NN*SCAP + 255)/256)    // 256

__global__ __launch_bounds__(256, 8) void kt_transpose(
        const int* __restrict__ bcnt, const int* __restrict__ bbeid,
        const float* __restrict__ elog_b, float* __restrict__ elb_csr,
        const int* __restrict__ scnt, const int* __restrict__ sbeid,
        const float* __restrict__ elog_s, float* __restrict__ els_csr) {
    int blk = blockIdx.x;
    if (blk < TSB_NB) {
        unsigned slot = (unsigned)blk * 256 + threadIdx.x;
        unsigned node = slot >> 7;          // BCAP = 128
        unsigned k = slot & (BCAP - 1);
        if ((int)k < bcnt[node]) {          // k < 128 always, so bcnt>BCAP still safe
            unsigned eid = (unsigned)bbeid[slot];
            #pragma unroll
            for (int b = 0; b < BB; ++b)
                elb_csr[(size_t)b * (NG * BCAP) + slot] = elog_b[(size_t)b * EBN + eid];
        }
    } else {
        unsigned slot = (unsigned)(blk - TSB_NB) * 256 + threadIdx.x;
        if (slot < NN * SCAP) {
            unsigned node = slot >> 7;      // SCAP = 128
            unsigned k = slot & (SCAP - 1);
            if ((int)k < scnt[node]) {
                unsigned eid = (unsigned)sbeid[slot];
                #pragma unroll
                for (int b = 0; b < BB; ++b)
                    els_csr[(size_t)b * (NN * SCAP) + slot] = elog_s[(size_t)b * ESN + eid];
            }
        }
    }
}

// ---------------- accumulation: p (f16, LDS) x h (f16, global) via v_fma_mix ------
__device__ __forceinline__ float accum_f16(const unsigned short* pArr,
                                           const unsigned int* oArr,
                                           int deg, const char* __restrict__ hB,
                                           unsigned int cl2,
                                           unsigned int& psum2) {
    float a0 = 0.f, a1 = 0.f;
    const uint4* pv = (const uint4*)pArr;   // 8 f16 per uint4
    const uint4* ov = (const uint4*)oArr;   // 4 offsets per uint4
    int ng8 = (deg + 7) >> 3;
    for (int j = 0; j < ng8; ++j) {
        uint4 pq = pv[j];
        uint4 oa = ov[2*j];
        uint4 ob = ov[2*j+1];
        unsigned int h0 = *(const unsigned short*)(hB + (oa.x + cl2));
        unsigned int h1 = *(const unsigned short*)(hB + (oa.y + cl2));
        unsigned int h2 = *(const unsigned short*)(hB + (oa.z + cl2));
        unsigned int h3 = *(const unsigned short*)(hB + (oa.w + cl2));
        unsigned int h4 = *(const unsigned short*)(hB + (ob.x + cl2));
        unsigned int h5 = *(const unsigned short*)(hB + (ob.y + cl2));
        unsigned int h6 = *(const unsigned short*)(hB + (ob.z + cl2));
        unsigned int h7 = *(const unsigned short*)(hB + (ob.w + cl2));
        asm("v_pk_add_f16 %0, %0, %1" : "+v"(psum2) : "v"(pq.x));
        asm("v_pk_add_f16 %0, %0, %1" : "+v"(psum2) : "v"(pq.y));
        asm("v_pk_add_f16 %0, %0, %1" : "+v"(psum2) : "v"(pq.z));
        asm("v_pk_add_f16 %0, %0, %1" : "+v"(psum2) : "v"(pq.w));
        asm("v_fma_mix_f32 %0, %1, %2, %0 op_sel:[0,0,0] op_sel_hi:[1,1,0]" : "+v"(a0) : "v"(pq.x), "v"(h0));
        asm("v_fma_mix_f32 %0, %1, %2, %0 op_sel:[1,0,0] op_sel_hi:[1,1,0]" : "+v"(a1) : "v"(pq.x), "v"(h1));
        asm("v_fma_mix_f32 %0, %1, %2, %0 op_sel:[0,0,0] op_sel_hi:[1,1,0]" : "+v"(a0) : "v"(pq.y), "v"(h2));
        asm("v_fma_mix_f32 %0, %1, %2, %0 op_sel:[1,0,0] op_sel_hi:[1,1,0]" : "+v"(a1) : "v"(pq.y), "v"(h3));
        asm("v_fma_mix_f32 %0, %1, %2, %0 op_sel:[0,0,0] op_sel_hi:[1,1,0]" : "+v"(a0) : "v"(pq.z), "v"(h4));
        asm("v_fma_mix_f32 %0, %1, %2, %0 op_sel:[1,0,0] op_sel_hi:[1,1,0]" : "+v"(a1) : "v"(pq.z), "v"(h5));
        asm("v_fma_mix_f32 %0, %1, %2, %0 op_sel:[0,0,0] op_sel_hi:[1,1,0]" : "+v"(a0) : "v"(pq.w), "v"(h6));
        asm("v_fma_mix_f32 %0, %1, %2, %0 op_sel:[1,0,0] op_sel_hi:[1,1,0]" : "+v"(a1) : "v"(pq.w), "v"(h7));
    }
    return a0 + a1;
}

// rare fallback: degree > 64 (chunked, no-max softmax, fp32 sum)
__device__ __noinline__ float gat_big(const int* __restrict__ buck,
                                      const float* __restrict__ elc, int deg,
                                      const float* __restrict__ asrc,
                                      const char* __restrict__ hB,
                                      float adg, int lane, unsigned int cl2,
                                      unsigned short* pArr, unsigned int* oArr) {
    if (deg <= 0) return 0.f;
    float acc = 0.f, sum = 0.f;
    for (int k0 = 0; k0 < deg; k0 += 64) {
        int k = k0 + lane;
        bool v = k < deg;
        unsigned idx = v ? (unsigned)k : 0u;
        unsigned s = (unsigned)buck[idx];
        float lg = asrc[s] + adg + elc[idx];
        lg = fmaxf(lg, 0.2f * lg);
        float p = v ? __expf(lg) : 0.f;
        asm volatile("s_waitcnt lgkmcnt(0)" ::: "memory");
        pArr[lane] = __half_as_ushort(__float2half(p));
        oArr[lane] = s * HROW;
        sum += wave_sum(p);
        asm volatile("s_waitcnt lgkmcnt(0)" ::: "memory");
        int valid = (deg - k0) < 64 ? (deg - k0) : 64;
        unsigned int dummy = 0;
        acc += accum_f16(pArr, oArr, valid, hB, cl2, dummy);
    }
    return acc * __builtin_amdgcn_rcpf(sum + 1e-16f);
}

// ---------------- K2: fused gather, XCD-pinned by batch (b = blockIdx & 7) ----------------
__global__ __launch_bounds__(256, 8) void k2_gather(
        const int* __restrict__ bcnt, const int* __restrict__ bbuck,
        const float* __restrict__ elb_csr,
        const int* __restrict__ scnt, const int* __restrict__ sbuck,
        const float* __restrict__ els_csr,
        const unsigned short* __restrict__ h_b, const unsigned short* __restrict__ h_s,
        const float* __restrict__ asb, const float* __restrict__ adb,
        const float* __restrict__ ass, const float* __restrict__ ads,
        const float* __restrict__ bias_b, const float* __restrict__ bias_s,
        const float* __restrict__ P, float* __restrict__ out) {
    __shared__ __align__(16) unsigned short pLds[4][2][64];  // f16 p per edge slot
    __shared__ __align__(16) unsigned int   oLds[4][2][64];  // prescaled byte offsets
    int blk = blockIdx.x;
    int b = blk & 7;                               // XCD pin: round-robin blk->XCD
    int w = threadIdx.x >> 6;
    unsigned int g = (((unsigned)blk >> 3) << 2) + w;
    unsigned int lane = threadIdx.x & 63;
    unsigned int cl2 = (lane < CC ? lane : 0) * 2;

    int degb = bcnt[g];  degb = degb < BCAP ? degb : BCAP;
    unsigned int sct = g >> 9;            // NN = 2^9
    unsigned int n = g & (NN - 1);
    int degs = scnt[n];  degs = degs < SCAP ? degs : SCAP;

    const int* bb = bbuck + (size_t)g * BCAP;
    const float* elbp = elb_csr + (size_t)b * (NG * BCAP) + (size_t)g * BCAP;
    const int* sb = sbuck + (size_t)n * SCAP;
    const float* elsp = els_csr + (size_t)b * (NN * SCAP) + (size_t)n * SCAP;
    const float* asrcb = asb + (size_t)b * NG;
    const char* hbB = (const char*)(h_b + (size_t)b * NG * CC);
    size_t basebg = (size_t)b * NG + (size_t)sct * NN;
    const float* asrcs = ass + basebg;
    const char* hsB = (const char*)(h_s + basebg * CC);
    float adgb = adb[(size_t)b * NG + g];
    float adgs = ads[basebg + n];

    float vb, vs;
    if (degb <= 64 && degs <= 64) {
        bool vB = lane < (unsigned)degb, vS = lane < (unsigned)degs;
        unsigned slb = vB ? lane : 0u;
        unsigned sls = vS ? lane : 0u;
        unsigned srcb = (unsigned)bb[slb];           // coalesced 4B
        unsigned srcs = (unsigned)sb[sls];
        float elbv = elbp[slb];                      // coalesced 4B
        float elsv = elsp[sls];
        float lgb = asrcb[srcb] + adgb + elbv;
        float lgs = asrcs[srcs] + adgs + elsv;
        lgb = fmaxf(lgb, 0.2f * lgb);                // leaky(0.2): max(x, 0.2x)
        lgs = fmaxf(lgs, 0.2f * lgs);
        float pb = vB ? __expf(lgb) : 0.f;           // logits bounded: no max-sub needed
        float ps = vS ? __expf(lgs) : 0.f;
        pLds[w][0][lane] = __half_as_ushort(__float2half(pb));
        pLds[w][1][lane] = __half_as_ushort(__float2half(ps));
        oLds[w][0][lane] = srcb * HROW;
        oLds[w][1][lane] = srcs * HROW;
        asm volatile("s_waitcnt lgkmcnt(0)" ::: "memory");
        unsigned int psumb = 0u, psums = 0u;
        float accb = accum_f16(&pLds[w][0][0], &oLds[w][0][0], degb, hbB, cl2, psumb);
        float accs = accum_f16(&pLds[w][1][0], &oLds[w][1][0], degs, hsB, cl2, psums);
        __half2 hb2 = __builtin_bit_cast(__half2, psumb);
        __half2 hs2 = __builtin_bit_cast(__half2, psums);
        float sumb = __low2float(hb2) + __high2float(hb2);
        float sums = __low2float(hs2) + __high2float(hs2);
        vb = accb * __builtin_amdgcn_rcpf(sumb + 1e-16f);
        vs = accs * __builtin_amdgcn_rcpf(sums + 1e-16f);
    } else {
        vb = gat_big(bb, elbp, degb, asrcb, hbB, adgb, lane, cl2,
                     &pLds[w][0][0], &oLds[w][0][0]);
        vs = gat_big(sb, elsp, degs, asrcs, hsB, adgs, lane, cl2,
                     &pLds[w][1][0], &oLds[w][1][0]);
    }

    if (lane < CC) {
        float ob = vb + bias_b[lane];
        ob = fmaxf(ob, 0.01f * ob);          // leaky(0.01)
        float os = vs + bias_s[lane];
        out[((size_t)b * NG + g) * CC + lane] = P[10] * ob + P[11] * os;
    }
}

extern "C" void kernel_launch(void* const* d_in, const int* in_sizes, int n_in,
                              void* d_out, int out_size, void* d_ws, size_t ws_size,
                              hipStream_t stream) {
    const float* x          = (const float*)d_in[0];
    const int*   bend_ei    = (const int*)d_in[1];
    const int*   sec_ei     = (const int*)d_in[2];
    const float* bend_attr  = (const float*)d_in[3];
    const float* sec_attr   = (const float*)d_in[4];
    const float* enc_W      = (const float*)d_in[5];
    const float* enc_b      = (const float*)d_in[6];
    const float* Wb         = (const float*)d_in[7];
    const float* a_src_b    = (const float*)d_in[8];
    const float* a_dst_b    = (const float*)d_in[9];
    const float* We_b       = (const float*)d_in[10];
    const float* a_e_b      = (const float*)d_in[11];
    const float* bias_b     = (const float*)d_in[12];
    const float* Ws         = (const float*)d_in[13];
    const float* a_src_s    = (const float*)d_in[14];
    const float* a_dst_s    = (const float*)d_in[15];
    const float* We_s       = (const float*)d_in[16];
    const float* a_e_s      = (const float*)d_in[17];
    const float* bias_s     = (const float*)d_in[18];
    const float* mix_w      = (const float*)d_in[19];
    float* out = (float*)d_out;

    char* base = (char*)d_ws;
    size_t off = 0;
    auto alloc = [&](size_t bytes) -> char* {
        off = (off + 255) & ~(size_t)255;
        char* p = base + off;
        off += bytes;
        return p;
    };
    float* P        = (float*)alloc(128 * sizeof(float));
    int* bcnt       = (int*)alloc((NG + NN) * sizeof(int));   // contiguous: one zero pass
    int* scnt       = bcnt + NG;
    int* bbuck      = (int*)alloc((size_t)NG * BCAP * sizeof(int));
    int* bbeid      = (int*)alloc((size_t)NG * BCAP * sizeof(int));
    int* sbuck      = (int*)alloc((size_t)NN * SCAP * sizeof(int));
    int* sbeid      = (int*)alloc((size_t)NN * SCAP * sizeof(int));
    float* elog_b   = (float*)alloc((size_t)BB * EBN * sizeof(float));
    float* elog_s   = (float*)alloc((size_t)BB * ESN * sizeof(float));
    float* elb_csr  = (float*)alloc((size_t)BB * NG * BCAP * sizeof(float));
    float* els_csr  = (float*)alloc((size_t)BB * NN * SCAP * sizeof(float));
    unsigned short* h_b = (unsigned short*)alloc((size_t)BB * NG * CC * sizeof(unsigned short));
    unsigned short* h_s = (unsigned short*)alloc((size_t)BB * NG * CC * sizeof(unsigned short));
    float* asb      = (float*)alloc((size_t)BB * NG * sizeof(float));
    float* adb      = (float*)alloc((size_t)BB * NG * sizeof(float));
    float* ass      = (float*)alloc((size_t)BB * NG * sizeof(float));
    float* ads      = (float*)alloc((size_t)BB * NG * sizeof(float));
    (void)ws_size; (void)in_sizes; (void)n_in; (void)out_size;

    k0_init<<<(NG + NN + 255) / 256, 256, 0, stream>>>(enc_W, enc_b,
                                                       Wb, a_src_b, a_dst_b, We_b, a_e_b,
                                                       Ws, a_src_s, a_dst_s, We_s, a_e_s,
                                                       mix_w, P, bcnt);

    int k1_blocks = FEAT_NB + FILLB_NB + FILLS_NB + ELOG_NB;
    k1_all<<<k1_blocks, 256, 0, stream>>>(x, bend_ei, sec_ei, bend_attr, sec_attr,
                                          Wb, Ws, P, h_b, h_s, asb, adb, ass, ads,
                                          elog_b, elog_s,
                                          bcnt, bbuck, bbeid, scnt, sbuck, sbeid);

    kt_transpose<<<TSB_NB + TSS_NB, 256, 0, stream>>>(bcnt, bbeid, elog_b, elb_csr,
                                                      scnt, sbeid, elog_s, els_csr);

    int k2_blocks = 8 * (NG / 4);   // b = blk & 7, 4 nodes per block
    k2_gather<<<k2_blocks, 256, 0, stream>>>(bcnt, bbuck, elb_csr, scnt, sbuck, els_csr,
                                             h_b, h_s, asb, adb, ass, ads,
                                             bias_b, bias_s, P, out);
}

// Round 15
// 127.065 us; speedup vs baseline: 1.2132x; 1.2132x over previous
//
#include <hip/hip_runtime.h>
#include <hip/hip_fp16.h>
#include <math.h>

// Problem dims
#define BB 8
#define SS 32
#define NN 512
#define FIN 24
#define CC 56
#define EBN 262144
#define ESN 8192
#define EDD 4
#define NG (SS*NN)   // 16384 nodes per sample in bend graph
#define BCAP 128     // bucket capacity (avg deg 16, Poisson-tail max ~45)
#define SCAP 128
#define HROW (CC*2)  // h row bytes (fp16)

// ---------------- small helpers ----------------
__device__ __forceinline__ float wave_sum(float v) {
    #pragma unroll
    for (int o = 32; o > 0; o >>= 1) v += __shfl_xor(v, o);
    return v;
}

// ---------------- K0: prep params + zero bucket counts ----------------
// P layout: [0..3]=u_bend, [4]=c_bend, [5..8]=u_sec, [9]=c_sec, [10]=w0, [11]=w1
//           [16..39]=wa_src_b, [40..63]=wa_dst_b, [64..87]=wa_src_s, [88..111]=wa_dst_s
__global__ void k0_init(const float* enc_W, const float* enc_b,
                        const float* Wb, const float* a_src_b, const float* a_dst_b,
                        const float* We_b, const float* a_e_b,
                        const float* Ws, const float* a_src_s, const float* a_dst_s,
                        const float* We_s, const float* a_e_s,
                        const float* mix_w, float* P, int* cnts) {
    int i = blockIdx.x * blockDim.x + threadIdx.x;
    if (i < NG + NN) cnts[i] = 0;          // bcnt | scnt contiguous
    if (blockIdx.x == 0) {
        int t = threadIdx.x;
        if (t < 96) {
            // fold W @ a vectors: P[16 + v*24 + f] = sum_c W[f][c] * a[c]
            int v = t / FIN, f = t % FIN;
            const float* W = (v < 2) ? Wb : Ws;
            const float* a = (v == 0) ? a_src_b : (v == 1) ? a_dst_b
                           : (v == 2) ? a_src_s : a_dst_s;
            float d = 0.f;
            for (int c = 0; c < CC; ++c) d = fmaf(W[f*CC + c], a[c], d);
            P[16 + t] = d;
        }
        if (t == 0) {
            float tb[EDD], ts[EDD];
            for (int j = 0; j < EDD; ++j) {
                float vb = 0.f, vs = 0.f;
                for (int c = 0; c < CC; ++c) {
                    vb += We_b[j*CC + c] * a_e_b[c];
                    vs += We_s[j*CC + c] * a_e_s[c];
                }
                tb[j] = vb; ts[j] = vs;
            }
            float cb = 0.f, cs = 0.f;
            for (int j = 0; j < EDD; ++j) { cb += enc_b[j]*tb[j]; cs += enc_b[j]*ts[j]; }
            for (int d = 0; d < EDD; ++d) {
                float ub = 0.f, us = 0.f;
                for (int j = 0; j < EDD; ++j) {
                    ub += enc_W[d*EDD + j] * tb[j];
                    us += enc_W[d*EDD + j] * ts[j];
                }
                P[d] = ub; P[5 + d] = us;
            }
            P[4] = cb; P[9] = cs;
            float m0 = mix_w[0], m1 = mix_w[1];
            float mm = fmaxf(m0, m1);
            float e0 = expf(m0 - mm), e1 = expf(m1 - mm);
            float inv = 1.f / (e0 + e1);
            P[10] = e0 * inv; P[11] = e1 * inv;
        }
    }
}

// ---------------- K1: feat (LDS-staged) + fill with batch-interleaved f16 el_csr --
#define FNB 64                          // nodes per feat block
#define FEAT_NB (BB*NG/FNB)             // 2048 blocks; 16 nodes/wave
#define FILLB_NB ((EBN+255)/256)        // 1024
#define FILLS_NB ((ESN+255)/256)        // 32

__global__ __launch_bounds__(256, 4) void k1_all(
        const float* __restrict__ x,
        const int* __restrict__ bend_ei, const int* __restrict__ sec_ei,
        const float* __restrict__ bend_attr, const float* __restrict__ sec_attr,
        const float* __restrict__ Wb, const float* __restrict__ Ws,
        const float* __restrict__ P,
        unsigned short* __restrict__ h_b, unsigned short* __restrict__ h_s,
        float* __restrict__ asb, float* __restrict__ adb,
        float* __restrict__ ass, float* __restrict__ ads,
        int* __restrict__ bcnt, int* __restrict__ bbuck, uint4* __restrict__ elb16,
        int* __restrict__ scnt, int* __restrict__ sbuck, uint4* __restrict__ els16) {
    __shared__ float xs[FNB * FIN];     // 6 KB x slab (feat branch only)
    int blk = blockIdx.x;
    int t = threadIdx.x;
    if (blk < FEAT_NB) {
        // ---- node features: stage x slab, then one matrix per pass (wc[24] live)
        const float4* xg = (const float4*)(x + (size_t)blk * FNB * FIN);
        float4* xs4 = (float4*)xs;
        #pragma unroll
        for (int i = 0; i < (FNB*FIN/4 + 255) / 256; ++i) {
            int idx = t + i * 256;
            if (idx < FNB*FIN/4) xs4[idx] = xg[idx];
        }
        int w = t >> 6, lane = t & 63;
        int nl0 = w * (FNB / 4);            // 16 nodes per wave
        __syncthreads();
        #pragma unroll 1
        for (int m = 0; m < 2; ++m) {
            const float* W = m ? Ws : Wb;
            unsigned short* h = m ? h_s : h_b;
            float* asx = m ? ass : asb;
            float* adx = m ? ads : adb;
            // pseudo-channels: lane 56 -> alpha_src, lane 57 -> alpha_dst (folded W@a)
            float wc[FIN];
            #pragma unroll
            for (int f = 0; f < FIN; ++f) {
                float v = 0.f;
                if (lane < CC) v = W[f*CC + lane];
                else if (lane < 58) v = P[16 + m*48 + (lane - 56)*FIN + f];
                wc[f] = v;
            }
            #pragma unroll 2
            for (int n0 = 0; n0 < FNB / 4; ++n0) {
                int nl = nl0 + n0;
                size_t node = (size_t)blk * FNB + nl;
                const float4* xr = (const float4*)(xs + nl * FIN);
                float acc = 0.f;
                #pragma unroll
                for (int q = 0; q < FIN/4; ++q) {
                    float4 v = xr[q];           // broadcast ds_read_b128
                    acc = fmaf(v.x, wc[4*q+0], acc);
                    acc = fmaf(v.y, wc[4*q+1], acc);
                    acc = fmaf(v.z, wc[4*q+2], acc);
                    acc = fmaf(v.w, wc[4*q+3], acc);
                }
                if (lane < CC) h[node*CC + lane] = __half_as_ushort(__float2half(acc));
                else if (lane == 56) asx[node] = acc;
                else if (lane == 57) adx[node] = acc;
            }
        }
    } else if (blk < FEAT_NB + FILLB_NB) {
        // ---- bend bucket fill + batch-interleaved f16 edge logits (one 16B store)
        int i = (blk - FEAT_NB) * 256 + t;
        if (i < EBN) {
            int s = bend_ei[i];
            int d = bend_ei[EBN + i];
            int p = atomicAdd(&bcnt[d], 1);
            if (p < BCAP) {
                unsigned slot = (unsigned)d * BCAP + (unsigned)p;
                bbuck[slot] = s;
                unsigned pk[4];
                #pragma unroll
                for (int q = 0; q < 4; ++q) {
                    float4 a0 = ((const float4*)bend_attr)[(size_t)(2*q) * EBN + i];
                    float4 a1 = ((const float4*)bend_attr)[(size_t)(2*q+1) * EBN + i];
                    float e0 = fmaf(a0.x, P[0], fmaf(a0.y, P[1], fmaf(a0.z, P[2], fmaf(a0.w, P[3], P[4]))));
                    float e1 = fmaf(a1.x, P[0], fmaf(a1.y, P[1], fmaf(a1.z, P[2], fmaf(a1.w, P[3], P[4]))));
                    pk[q] = (unsigned)__half_as_ushort(__float2half(e0))
                          | ((unsigned)__half_as_ushort(__float2half(e1)) << 16);
                }
                elb16[slot] = make_uint4(pk[0], pk[1], pk[2], pk[3]);
            }
        }
    } else {
        // ---- section bucket fill + batch-interleaved f16 edge logits
        int i = (blk - FEAT_NB - FILLB_NB) * 256 + t;
        if (i < ESN) {
            int s = sec_ei[i];
            int d = sec_ei[ESN + i];
            int p = atomicAdd(&scnt[d], 1);
            if (p < SCAP) {
                unsigned slot = (unsigned)d * SCAP + (unsigned)p;
                sbuck[slot] = s;
                unsigned pk[4];
                #pragma unroll
                for (int q = 0; q < 4; ++q) {
                    float4 a0 = ((const float4*)sec_attr)[(size_t)(2*q) * ESN + i];
                    float4 a1 = ((const float4*)sec_attr)[(size_t)(2*q+1) * ESN + i];
                    float e0 = fmaf(a0.x, P[5], fmaf(a0.y, P[6], fmaf(a0.z, P[7], fmaf(a0.w, P[8], P[9]))));
                    float e1 = fmaf(a1.x, P[5], fmaf(a1.y, P[6], fmaf(a1.z, P[7], fmaf(a1.w, P[8], P[9]))));
                    pk[q] = (unsigned)__half_as_ushort(__float2half(e0))
                          | ((unsigned)__half_as_ushort(__float2half(e1)) << 16);
                }
                els16[slot] = make_uint4(pk[0], pk[1], pk[2], pk[3]);
            }
        }
    }
}

// ---------------- accumulation: p (f16, LDS) x h (f16, global) via v_fma_mix ------
__device__ __forceinline__ float accum_f16(const unsigned short* pArr,
                                           const unsigned int* oArr,
                                           int deg, const char* __restrict__ hB,
                                           unsigned int cl2,
                                           unsigned int& psum2) {
    float a0 = 0.f, a1 = 0.f;
    const uint4* pv = (const uint4*)pArr;   // 8 f16 per uint4
    const uint4* ov = (const uint4*)oArr;   // 4 offsets per uint4
    int ng8 = (deg + 7) >> 3;
    for (int j = 0; j < ng8; ++j) {
        uint4 pq = pv[j];
        uint4 oa = ov[2*j];
        uint4 ob = ov[2*j+1];
        unsigned int h0 = *(const unsigned short*)(hB + (oa.x + cl2));
        unsigned int h1 = *(const unsigned short*)(hB + (oa.y + cl2));
        unsigned int h2 = *(const unsigned short*)(hB + (oa.z + cl2));
        unsigned int h3 = *(const unsigned short*)(hB + (oa.w + cl2));
        unsigned int h4 = *(const unsigned short*)(hB + (ob.x + cl2));
        unsigned int h5 = *(const unsigned short*)(hB + (ob.y + cl2));
        unsigned int h6 = *(const unsigned short*)(hB + (ob.z + cl2));
        unsigned int h7 = *(const unsigned short*)(hB + (ob.w + cl2));
        asm("v_pk_add_f16 %0, %0, %1" : "+v"(psum2) : "v"(pq.x));
        asm("v_pk_add_f16 %0, %0, %1" : "+v"(psum2) : "v"(pq.y));
        asm("v_pk_add_f16 %0, %0, %1" : "+v"(psum2) : "v"(pq.z));
        asm("v_pk_add_f16 %0, %0, %1" : "+v"(psum2) : "v"(pq.w));
        asm("v_fma_mix_f32 %0, %1, %2, %0 op_sel:[0,0,0] op_sel_hi:[1,1,0]" : "+v"(a0) : "v"(pq.x), "v"(h0));
        asm("v_fma_mix_f32 %0, %1, %2, %0 op_sel:[1,0,0] op_sel_hi:[1,1,0]" : "+v"(a1) : "v"(pq.x), "v"(h1));
        asm("v_fma_mix_f32 %0, %1, %2, %0 op_sel:[0,0,0] op_sel_hi:[1,1,0]" : "+v"(a0) : "v"(pq.y), "v"(h2));
        asm("v_fma_mix_f32 %0, %1, %2, %0 op_sel:[1,0,0] op_sel_hi:[1,1,0]" : "+v"(a1) : "v"(pq.y), "v"(h3));
        asm("v_fma_mix_f32 %0, %1, %2, %0 op_sel:[0,0,0] op_sel_hi:[1,1,0]" : "+v"(a0) : "v"(pq.z), "v"(h4));
        asm("v_fma_mix_f32 %0, %1, %2, %0 op_sel:[1,0,0] op_sel_hi:[1,1,0]" : "+v"(a1) : "v"(pq.z), "v"(h5));
        asm("v_fma_mix_f32 %0, %1, %2, %0 op_sel:[0,0,0] op_sel_hi:[1,1,0]" : "+v"(a0) : "v"(pq.w), "v"(h6));
        asm("v_fma_mix_f32 %0, %1, %2, %0 op_sel:[1,0,0] op_sel_hi:[1,1,0]" : "+v"(a1) : "v"(pq.w), "v"(h7));
    }
    return a0 + a1;
}

// rare fallback: degree > 64 (chunked, no-max softmax, fp32 sum)
// elc pre-offset to batch b; el value at slot k is elc[k*8]
__device__ __noinline__ float gat_big(const int* __restrict__ buck,
                                      const unsigned short* __restrict__ elc, int deg,
                                      const float* __restrict__ asrc,
                                      const char* __restrict__ hB,
                                      float adg, int lane, unsigned int cl2,
                                      unsigned short* pArr, unsigned int* oArr) {
    if (deg <= 0) return 0.f;
    float acc = 0.f, sum = 0.f;
    for (int k0 = 0; k0 < deg; k0 += 64) {
        int k = k0 + lane;
        bool v = k < deg;
        unsigned idx = v ? (unsigned)k : 0u;
        unsigned s = (unsigned)buck[idx];
        float el = __half2float(__ushort_as_half(elc[(size_t)idx * 8]));
        float lg = asrc[s] + adg + el;
        lg = fmaxf(lg, 0.2f * lg);
        float p = v ? __expf(lg) : 0.f;
        asm volatile("s_waitcnt lgkmcnt(0)" ::: "memory");
        pArr[lane] = __half_as_ushort(__float2half(p));
        oArr[lane] = s * HROW;
        sum += wave_sum(p);
        asm volatile("s_waitcnt lgkmcnt(0)" ::: "memory");
        int valid = (deg - k0) < 64 ? (deg - k0) : 64;
        unsigned int dummy = 0;
        acc += accum_f16(pArr, oArr, valid, hB, cl2, dummy);
    }
    return acc * __builtin_amdgcn_rcpf(sum + 1e-16f);
}

// ---------------- K2: fused gather, XCD-pinned by batch (b = blockIdx & 7) ----------------
__global__ __launch_bounds__(256, 8) void k2_gather(
        const int* __restrict__ bcnt, const int* __restrict__ bbuck,
        const unsigned short* __restrict__ elb16,
        const int* __restrict__ scnt, const int* __restrict__ sbuck,
        const unsigned short* __restrict__ els16,
        const unsigned short* __restrict__ h_b, const unsigned short* __restrict__ h_s,
        const float* __restrict__ asb, const float* __restrict__ adb,
        const float* __restrict__ ass, const float* __restrict__ ads,
        const float* __restrict__ bias_b, const float* __restrict__ bias_s,
        const float* __restrict__ P, float* __restrict__ out) {
    __shared__ __align__(16) unsigned short pLds[4][2][64];  // f16 p per edge slot
    __shared__ __align__(16) unsigned int   oLds[4][2][64];  // prescaled byte offsets
    int blk = blockIdx.x;
    int b = blk & 7;                               // XCD pin: round-robin blk->XCD
    int w = threadIdx.x >> 6;
    unsigned int g = (((unsigned)blk >> 3) << 2) + w;
    unsigned int lane = threadIdx.x & 63;
    unsigned int cl2 = (lane < CC ? lane : 0) * 2;

    int degb = bcnt[g];  degb = degb < BCAP ? degb : BCAP;
    unsigned int sct = g >> 9;            // NN = 2^9
    unsigned int n = g & (NN - 1);
    int degs = scnt[n];  degs = degs < SCAP ? degs : SCAP;

    const int* bb = bbuck + (size_t)g * BCAP;
    const unsigned short* elbp = elb16 + (size_t)g * BCAP * 8 + b;   // value at slot k: elbp[k*8]
    const int* sb = sbuck + (size_t)n * SCAP;
    const unsigned short* elsp = els16 + (size_t)n * SCAP * 8 + b;
    const float* asrcb = asb + (size_t)b * NG;
    const char* hbB = (const char*)(h_b + (size_t)b * NG * CC);
    size_t basebg = (size_t)b * NG + (size_t)sct * NN;
    const float* asrcs = ass + basebg;
    const char* hsB = (const char*)(h_s + basebg * CC);
    float adgb = adb[(size_t)b * NG + g];
    float adgs = ads[basebg + n];

    float vb, vs;
    if (degb <= 64 && degs <= 64) {
        bool vB = lane < (unsigned)degb, vS = lane < (unsigned)degs;
        unsigned slb = vB ? lane : 0u;
        unsigned sls = vS ? lane : 0u;
        unsigned srcb = (unsigned)bb[slb];           // coalesced 4B
        unsigned srcs = (unsigned)sb[sls];
        float elbv = __half2float(__ushort_as_half(elbp[slb * 8]));  // coalesced 2B, stride 16B
        float elsv = __half2float(__ushort_as_half(elsp[sls * 8]));
        float lgb = asrcb[srcb] + adgb + elbv;
        float lgs = asrcs[srcs] + adgs + elsv;
        lgb = fmaxf(lgb, 0.2f * lgb);                // leaky(0.2): max(x, 0.2x)
        lgs = fmaxf(lgs, 0.2f * lgs);
        float pb = vB ? __expf(lgb) : 0.f;           // logits bounded: no max-sub needed
        float ps = vS ? __expf(lgs) : 0.f;
        pLds[w][0][lane] = __half_as_ushort(__float2half(pb));
        pLds[w][1][lane] = __half_as_ushort(__float2half(ps));
        oLds[w][0][lane] = srcb * HROW;
        oLds[w][1][lane] = srcs * HROW;
        asm volatile("s_waitcnt lgkmcnt(0)" ::: "memory");
        unsigned int psumb = 0u, psums = 0u;
        float accb = accum_f16(&pLds[w][0][0], &oLds[w][0][0], degb, hbB, cl2, psumb);
        float accs = accum_f16(&pLds[w][1][0], &oLds[w][1][0], degs, hsB, cl2, psums);
        __half2 hb2 = __builtin_bit_cast(__half2, psumb);
        __half2 hs2 = __builtin_bit_cast(__half2, psums);
        float sumb = __low2float(hb2) + __high2float(hb2);
        float sums = __low2float(hs2) + __high2float(hs2);
        vb = accb * __builtin_amdgcn_rcpf(sumb + 1e-16f);
        vs = accs * __builtin_amdgcn_rcpf(sums + 1e-16f);
    } else {
        vb = gat_big(bb, elbp, degb, asrcb, hbB, adgb, lane, cl2,
                     &pLds[w][0][0], &oLds[w][0][0]);
        vs = gat_big(sb, elsp, degs, asrcs, hsB, adgs, lane, cl2,
                     &pLds[w][1][0], &oLds[w][1][0]);
    }

    if (lane < CC) {
        float ob = vb + bias_b[lane];
        ob = fmaxf(ob, 0.01f * ob);          // leaky(0.01)
        float os = vs + bias_s[lane];
        out[((size_t)b * NG + g) * CC + lane] = P[10] * ob + P[11] * os;
    }
}

extern "C" void kernel_launch(void* const* d_in, const int* in_sizes, int n_in,
                              void* d_out, int out_size, void* d_ws, size_t ws_size,
                              hipStream_t stream) {
    const float* x          = (const float*)d_in[0];
    const int*   bend_ei    = (const int*)d_in[1];
    const int*   sec_ei     = (const int*)d_in[2];
    const float* bend_attr  = (const float*)d_in[3];
    const float* sec_attr   = (const float*)d_in[4];
    const float* enc_W      = (const float*)d_in[5];
    const float* enc_b      = (const float*)d_in[6];
    const float* Wb         = (const float*)d_in[7];
    const float* a_src_b    = (const float*)d_in[8];
    const float* a_dst_b    = (const float*)d_in[9];
    const float* We_b       = (const float*)d_in[10];
    const float* a_e_b      = (const float*)d_in[11];
    const float* bias_b     = (const float*)d_in[12];
    const float* Ws         = (const float*)d_in[13];
    const float* a_src_s    = (const float*)d_in[14];
    const float* a_dst_s    = (const float*)d_in[15];
    const float* We_s       = (const float*)d_in[16];
    const float* a_e_s      = (const float*)d_in[17];
    const float* bias_s     = (const float*)d_in[18];
    const float* mix_w      = (const float*)d_in[19];
    float* out = (float*)d_out;

    char* base = (char*)d_ws;
    size_t off = 0;
    auto alloc = [&](size_t bytes) -> char* {
        off = (off + 255) & ~(size_t)255;
        char* p = base + off;
        off += bytes;
        return p;
    };
    float* P        = (float*)alloc(128 * sizeof(float));
    int* bcnt       = (int*)alloc((NG + NN) * sizeof(int));   // contiguous: one zero pass
    int* scnt       = bcnt + NG;
    int* bbuck      = (int*)alloc((size_t)NG * BCAP * sizeof(int));
    int* sbuck      = (int*)alloc((size_t)NN * SCAP * sizeof(int));
    uint4* elb16    = (uint4*)alloc((size_t)NG * BCAP * sizeof(uint4));  // [slot][8 f16]
    uint4* els16    = (uint4*)alloc((size_t)NN * SCAP * sizeof(uint4));
    unsigned short* h_b = (unsigned short*)alloc((size_t)BB * NG * CC * sizeof(unsigned short));
    unsigned short* h_s = (unsigned short*)alloc((size_t)BB * NG * CC * sizeof(unsigned short));
    float* asb      = (float*)alloc((size_t)BB * NG * sizeof(float));
    float* adb      = (float*)alloc((size_t)BB * NG * sizeof(float));
    float* ass      = (float*)alloc((size_t)BB * NG * sizeof(float));
    float* ads      = (float*)alloc((size_t)BB * NG * sizeof(float));
    (void)ws_size; (void)in_sizes; (void)n_in; (void)out_size;

    k0_init<<<(NG + NN + 255) / 256, 256, 0, stream>>>(enc_W, enc_b,
                                                       Wb, a_src_b, a_dst_b, We_b, a_e_b,
                                                       Ws, a_src_s, a_dst_s, We_s, a_e_s,
                                                       mix_w, P, bcnt);

    int k1_blocks = FEAT_NB + FILLB_NB + FILLS_NB;
    k1_all<<<k1_blocks, 256, 0, stream>>>(x, bend_ei, sec_ei, bend_attr, sec_attr,
                                          Wb, Ws, P, h_b, h_s, asb, adb, ass, ads,
                                          bcnt, bbuck, elb16, scnt, sbuck, els16);

    int k2_blocks = 8 * (NG / 4);   // b = blk & 7, 4 nodes per block
    k2_gather<<<k2_blocks, 256, 0, stream>>>(bcnt, bbuck, (const unsigned short*)elb16,
                                             scnt, sbuck, (const unsigned short*)els16,
                                             h_b, h_s, asb, adb, ass, ads,
                                             bias_b, bias_s, P, out);
}

// Round 17
// 126.185 us; speedup vs baseline: 1.2217x; 1.0070x over previous
//
#include <hip/hip_runtime.h>
#include <hip/hip_fp16.h>
#include <math.h>

// Problem dims
#define BB 8
#define SS 32
#define NN 512
#define FIN 24
#define CC 56
#define EBN 262144
#define ESN 8192
#define EDD 4
#define NG (SS*NN)   // 16384 nodes per sample in bend graph
#define BCAP 128     // bucket capacity (avg deg 16, Poisson-tail max ~45)
#define SCAP 128
#define HROW (CC*2)  // h row bytes (fp16)

typedef unsigned int u32x4 __attribute__((ext_vector_type(4)));

// ---------------- small helpers ----------------
__device__ __forceinline__ float wave_sum(float v) {
    #pragma unroll
    for (int o = 32; o > 0; o >>= 1) v += __shfl_xor(v, o);
    return v;
}

// SRSRC buffer descriptor: base (48-bit VA), stride 0, no bounds check, raw dword.
// Base words pass through readfirstlane so the descriptor is provably wave-uniform
// and lands in SGPRs (required: SRSRC operand must be scalar regs).
__device__ __forceinline__ u32x4 make_rsrc(const void* p) {
    union { const void* p; unsigned int u[2]; } c; c.p = p;
    u32x4 r;
    r.x = __builtin_amdgcn_readfirstlane(c.u[0]);
    r.y = __builtin_amdgcn_readfirstlane(c.u[1] & 0xFFFFu);  // base[47:32]; stride=0
    r.z = 0xFFFFFFFFu;        // num_records: bounds check disabled
    r.w = 0x00020000u;        // raw untyped access
    return r;
}

// ---------------- K0: prep params + zero bucket counts ----------------
// P layout: [0..3]=u_bend, [4]=c_bend, [5..8]=u_sec, [9]=c_sec, [10]=w0, [11]=w1
//           [16..39]=wa_src_b, [40..63]=wa_dst_b, [64..87]=wa_src_s, [88..111]=wa_dst_s
__global__ void k0_init(const float* enc_W, const float* enc_b,
                        const float* Wb, const float* a_src_b, const float* a_dst_b,
                        const float* We_b, const float* a_e_b,
                        const float* Ws, const float* a_src_s, const float* a_dst_s,
                        const float* We_s, const float* a_e_s,
                        const float* mix_w, float* P, int* cnts) {
    int i = blockIdx.x * blockDim.x + threadIdx.x;
    if (i < NG + NN) cnts[i] = 0;          // bcnt | scnt contiguous
    if (blockIdx.x == 0) {
        int t = threadIdx.x;
        if (t < 96) {
            // fold W @ a vectors: P[16 + v*24 + f] = sum_c W[f][c] * a[c]
            int v = t / FIN, f = t % FIN;
            const float* W = (v < 2) ? Wb : Ws;
            const float* a = (v == 0) ? a_src_b : (v == 1) ? a_dst_b
                           : (v == 2) ? a_src_s : a_dst_s;
            float d = 0.f;
            for (int c = 0; c < CC; ++c) d = fmaf(W[f*CC + c], a[c], d);
            P[16 + t] = d;
        }
        if (t == 0) {
            float tb[EDD], ts[EDD];
            for (int j = 0; j < EDD; ++j) {
                float vb = 0.f, vs = 0.f;
                for (int c = 0; c < CC; ++c) {
                    vb += We_b[j*CC + c] * a_e_b[c];
                    vs += We_s[j*CC + c] * a_e_s[c];
                }
                tb[j] = vb; ts[j] = vs;
            }
            float cb = 0.f, cs = 0.f;
            for (int j = 0; j < EDD; ++j) { cb += enc_b[j]*tb[j]; cs += enc_b[j]*ts[j]; }
            for (int d = 0; d < EDD; ++d) {
                float ub = 0.f, us = 0.f;
                for (int j = 0; j < EDD; ++j) {
                    ub += enc_W[d*EDD + j] * tb[j];
                    us += enc_W[d*EDD + j] * ts[j];
                }
                P[d] = ub; P[5 + d] = us;
            }
            P[4] = cb; P[9] = cs;
            float m0 = mix_w[0], m1 = mix_w[1];
            float mm = fmaxf(m0, m1);
            float e0 = expf(m0 - mm), e1 = expf(m1 - mm);
            float inv = 1.f / (e0 + e1);
            P[10] = e0 * inv; P[11] = e1 * inv;
        }
    }
}

// ---------------- K1: feat (LDS-staged) + fill with batch-interleaved f16 el_csr --
#define FNB 64                          // nodes per feat block
#define FEAT_NB (BB*NG/FNB)             // 2048 blocks; 16 nodes/wave
#define FILLB_NB ((EBN+255)/256)        // 1024
#define FILLS_NB ((ESN+255)/256)        // 32

__global__ __launch_bounds__(256, 4) void k1_all(
        const float* __restrict__ x,
        const int* __restrict__ bend_ei, const int* __restrict__ sec_ei,
        const float* __restrict__ bend_attr, const float* __restrict__ sec_attr,
        const float* __restrict__ Wb, const float* __restrict__ Ws,
        const float* __restrict__ P,
        unsigned short* __restrict__ h_b, unsigned short* __restrict__ h_s,
        float* __restrict__ asb, float* __restrict__ adb,
        float* __restrict__ ass, float* __restrict__ ads,
        int* __restrict__ bcnt, int* __restrict__ bbuck, uint4* __restrict__ elb16,
        int* __restrict__ scnt, int* __restrict__ sbuck, uint4* __restrict__ els16) {
    __shared__ float xs[FNB * FIN];     // 6 KB x slab (feat branch only)
    int blk = blockIdx.x;
    int t = threadIdx.x;
    if (blk < FEAT_NB) {
        // ---- node features: stage x slab, then one matrix per pass (wc[24] live)
        const float4* xg = (const float4*)(x + (size_t)blk * FNB * FIN);
        float4* xs4 = (float4*)xs;
        #pragma unroll
        for (int i = 0; i < (FNB*FIN/4 + 255) / 256; ++i) {
            int idx = t + i * 256;
            if (idx < FNB*FIN/4) xs4[idx] = xg[idx];
        }
        int w = t >> 6, lane = t & 63;
        int nl0 = w * (FNB / 4);            // 16 nodes per wave
        __syncthreads();
        #pragma unroll 1
        for (int m = 0; m < 2; ++m) {
            const float* W = m ? Ws : Wb;
            unsigned short* h = m ? h_s : h_b;
            float* asx = m ? ass : asb;
            float* adx = m ? ads : adb;
            // pseudo-channels: lane 56 -> alpha_src, lane 57 -> alpha_dst (folded W@a)
            float wc[FIN];
            #pragma unroll
            for (int f = 0; f < FIN; ++f) {
                float v = 0.f;
                if (lane < CC) v = W[f*CC + lane];
                else if (lane < 58) v = P[16 + m*48 + (lane - 56)*FIN + f];
                wc[f] = v;
            }
            #pragma unroll 2
            for (int n0 = 0; n0 < FNB / 4; ++n0) {
                int nl = nl0 + n0;
                size_t node = (size_t)blk * FNB + nl;
                const float4* xr = (const float4*)(xs + nl * FIN);
                float acc = 0.f;
                #pragma unroll
                for (int q = 0; q < FIN/4; ++q) {
                    float4 v = xr[q];           // broadcast ds_read_b128
                    acc = fmaf(v.x, wc[4*q+0], acc);
                    acc = fmaf(v.y, wc[4*q+1], acc);
                    acc = fmaf(v.z, wc[4*q+2], acc);
                    acc = fmaf(v.w, wc[4*q+3], acc);
                }
                if (lane < CC) h[node*CC + lane] = __half_as_ushort(__float2half(acc));
                else if (lane == 56) asx[node] = acc;
                else if (lane == 57) adx[node] = acc;
            }
        }
    } else if (blk < FEAT_NB + FILLB_NB) {
        // ---- bend bucket fill + batch-interleaved f16 edge logits (one 16B store)
        int i = (blk - FEAT_NB) * 256 + t;
        if (i < EBN) {
            int s = bend_ei[i];
            int d = bend_ei[EBN + i];
            int p = atomicAdd(&bcnt[d], 1);
            if (p < BCAP) {
                unsigned slot = (unsigned)d * BCAP + (unsigned)p;
                bbuck[slot] = s;
                unsigned pk[4];
                #pragma unroll
                for (int q = 0; q < 4; ++q) {
                    float4 a0 = ((const float4*)bend_attr)[(size_t)(2*q) * EBN + i];
                    float4 a1 = ((const float4*)bend_attr)[(size_t)(2*q+1) * EBN + i];
                    float e0 = fmaf(a0.x, P[0], fmaf(a0.y, P[1], fmaf(a0.z, P[2], fmaf(a0.w, P[3], P[4]))));
                    float e1 = fmaf(a1.x, P[0], fmaf(a1.y, P[1], fmaf(a1.z, P[2], fmaf(a1.w, P[3], P[4]))));
                    pk[q] = (unsigned)__half_as_ushort(__float2half(e0))
                          | ((unsigned)__half_as_ushort(__float2half(e1)) << 16);
                }
                elb16[slot] = make_uint4(pk[0], pk[1], pk[2], pk[3]);
            }
        }
    } else {
        // ---- section bucket fill + batch-interleaved f16 edge logits
        int i = (blk - FEAT_NB - FILLB_NB) * 256 + t;
        if (i < ESN) {
            int s = sec_ei[i];
            int d = sec_ei[ESN + i];
            int p = atomicAdd(&scnt[d], 1);
            if (p < SCAP) {
                unsigned slot = (unsigned)d * SCAP + (unsigned)p;
                sbuck[slot] = s;
                unsigned pk[4];
                #pragma unroll
                for (int q = 0; q < 4; ++q) {
                    float4 a0 = ((const float4*)sec_attr)[(size_t)(2*q) * ESN + i];
                    float4 a1 = ((const float4*)sec_attr)[(size_t)(2*q+1) * ESN + i];
                    float e0 = fmaf(a0.x, P[5], fmaf(a0.y, P[6], fmaf(a0.z, P[7], fmaf(a0.w, P[8], P[9]))));
                    float e1 = fmaf(a1.x, P[5], fmaf(a1.y, P[6], fmaf(a1.z, P[7], fmaf(a1.w, P[8], P[9]))));
                    pk[q] = (unsigned)__half_as_ushort(__float2half(e0))
                          | ((unsigned)__half_as_ushort(__float2half(e1)) << 16);
                }
                els16[slot] = make_uint4(pk[0], pk[1], pk[2], pk[3]);
            }
        }
    }
}

// ---------------- accumulation (fast path): SRSRC buffer_load h-gather ------------
// pArr: 64 f16 p's; oArr: 64 pre-scaled byte offsets (src*HROW).
// 8 buffer_load_ushort per iter issued in one asm block (32-bit voffset, SGPR SRSRC),
// single vmcnt(0) drain; psum2 accumulates f16x2 pairwise sum of p.
__device__ __forceinline__ float accum_srsrc(const unsigned short* pArr,
                                             const unsigned int* oArr,
                                             int deg, u32x4 rsrc,
                                             unsigned int cl2,
                                             unsigned int& psum2) {
    float a0 = 0.f, a1 = 0.f;
    const uint4* pv = (const uint4*)pArr;   // 8 f16 per uint4
    const uint4* ov = (const uint4*)oArr;   // 4 offsets per uint4
    int ng8 = (deg + 7) >> 3;
    for (int j = 0; j < ng8; ++j) {
        uint4 pq = pv[j];
        uint4 oa = ov[2*j];
        uint4 ob = ov[2*j+1];
        unsigned int o0 = oa.x + cl2, o1 = oa.y + cl2, o2 = oa.z + cl2, o3 = oa.w + cl2;
        unsigned int o4 = ob.x + cl2, o5 = ob.y + cl2, o6 = ob.z + cl2, o7 = ob.w + cl2;
        unsigned int h0, h1, h2, h3, h4, h5, h6, h7;
        asm volatile(
            "buffer_load_ushort %0, %8, %16, 0 offen\n\t"
            "buffer_load_ushort %1, %9, %16, 0 offen\n\t"
            "buffer_load_ushort %2, %10, %16, 0 offen\n\t"
            "buffer_load_ushort %3, %11, %16, 0 offen\n\t"
            "buffer_load_ushort %4, %12, %16, 0 offen\n\t"
            "buffer_load_ushort %5, %13, %16, 0 offen\n\t"
            "buffer_load_ushort %6, %14, %16, 0 offen\n\t"
            "buffer_load_ushort %7, %15, %16, 0 offen\n\t"
            "s_waitcnt vmcnt(0)"
            : "=&v"(h0), "=&v"(h1), "=&v"(h2), "=&v"(h3),
              "=&v"(h4), "=&v"(h5), "=&v"(h6), "=&v"(h7)
            : "v"(o0), "v"(o1), "v"(o2), "v"(o3),
              "v"(o4), "v"(o5), "v"(o6), "v"(o7),
              "s"(rsrc));
        asm("v_pk_add_f16 %0, %0, %1" : "+v"(psum2) : "v"(pq.x));
        asm("v_pk_add_f16 %0, %0, %1" : "+v"(psum2) : "v"(pq.y));
        asm("v_pk_add_f16 %0, %0, %1" : "+v"(psum2) : "v"(pq.z));
        asm("v_pk_add_f16 %0, %0, %1" : "+v"(psum2) : "v"(pq.w));
        asm("v_fma_mix_f32 %0, %1, %2, %0 op_sel:[0,0,0] op_sel_hi:[1,1,0]" : "+v"(a0) : "v"(pq.x), "v"(h0));
        asm("v_fma_mix_f32 %0, %1, %2, %0 op_sel:[1,0,0] op_sel_hi:[1,1,0]" : "+v"(a1) : "v"(pq.x), "v"(h1));
        asm("v_fma_mix_f32 %0, %1, %2, %0 op_sel:[0,0,0] op_sel_hi:[1,1,0]" : "+v"(a0) : "v"(pq.y), "v"(h2));
        asm("v_fma_mix_f32 %0, %1, %2, %0 op_sel:[1,0,0] op_sel_hi:[1,1,0]" : "+v"(a1) : "v"(pq.y), "v"(h3));
        asm("v_fma_mix_f32 %0, %1, %2, %0 op_sel:[0,0,0] op_sel_hi:[1,1,0]" : "+v"(a0) : "v"(pq.z), "v"(h4));
        asm("v_fma_mix_f32 %0, %1, %2, %0 op_sel:[1,0,0] op_sel_hi:[1,1,0]" : "+v"(a1) : "v"(pq.z), "v"(h5));
        asm("v_fma_mix_f32 %0, %1, %2, %0 op_sel:[0,0,0] op_sel_hi:[1,1,0]" : "+v"(a0) : "v"(pq.w), "v"(h6));
        asm("v_fma_mix_f32 %0, %1, %2, %0 op_sel:[1,0,0] op_sel_hi:[1,1,0]" : "+v"(a1) : "v"(pq.w), "v"(h7));
    }
    return a0 + a1;
}

// pointer-based accum (fallback path only)
__device__ __forceinline__ float accum_f16(const unsigned short* pArr,
                                           const unsigned int* oArr,
                                           int deg, const char* __restrict__ hB,
                                           unsigned int cl2,
                                           unsigned int& psum2) {
    float a0 = 0.f, a1 = 0.f;
    const uint4* pv = (const uint4*)pArr;
    const uint4* ov = (const uint4*)oArr;
    int ng8 = (deg + 7) >> 3;
    for (int j = 0; j < ng8; ++j) {
        uint4 pq = pv[j];
        uint4 oa = ov[2*j];
        uint4 ob = ov[2*j+1];
        unsigned int h0 = *(const unsigned short*)(hB + (oa.x + cl2));
        unsigned int h1 = *(const unsigned short*)(hB + (oa.y + cl2));
        unsigned int h2 = *(const unsigned short*)(hB + (oa.z + cl2));
        unsigned int h3 = *(const unsigned short*)(hB + (oa.w + cl2));
        unsigned int h4 = *(const unsigned short*)(hB + (ob.x + cl2));
        unsigned int h5 = *(const unsigned short*)(hB + (ob.y + cl2));
        unsigned int h6 = *(const unsigned short*)(hB + (ob.z + cl2));
        unsigned int h7 = *(const unsigned short*)(hB + (ob.w + cl2));
        asm("v_pk_add_f16 %0, %0, %1" : "+v"(psum2) : "v"(pq.x));
        asm("v_pk_add_f16 %0, %0, %1" : "+v"(psum2) : "v"(pq.y));
        asm("v_pk_add_f16 %0, %0, %1" : "+v"(psum2) : "v"(pq.z));
        asm("v_pk_add_f16 %0, %0, %1" : "+v"(psum2) : "v"(pq.w));
        asm("v_fma_mix_f32 %0, %1, %2, %0 op_sel:[0,0,0] op_sel_hi:[1,1,0]" : "+v"(a0) : "v"(pq.x), "v"(h0));
        asm("v_fma_mix_f32 %0, %1, %2, %0 op_sel:[1,0,0] op_sel_hi:[1,1,0]" : "+v"(a1) : "v"(pq.x), "v"(h1));
        asm("v_fma_mix_f32 %0, %1, %2, %0 op_sel:[0,0,0] op_sel_hi:[1,1,0]" : "+v"(a0) : "v"(pq.y), "v"(h2));
        asm("v_fma_mix_f32 %0, %1, %2, %0 op_sel:[1,0,0] op_sel_hi:[1,1,0]" : "+v"(a1) : "v"(pq.y), "v"(h3));
        asm("v_fma_mix_f32 %0, %1, %2, %0 op_sel:[0,0,0] op_sel_hi:[1,1,0]" : "+v"(a0) : "v"(pq.z), "v"(h4));
        asm("v_fma_mix_f32 %0, %1, %2, %0 op_sel:[1,0,0] op_sel_hi:[1,1,0]" : "+v"(a1) : "v"(pq.z), "v"(h5));
        asm("v_fma_mix_f32 %0, %1, %2, %0 op_sel:[0,0,0] op_sel_hi:[1,1,0]" : "+v"(a0) : "v"(pq.w), "v"(h6));
        asm("v_fma_mix_f32 %0, %1, %2, %0 op_sel:[1,0,0] op_sel_hi:[1,1,0]" : "+v"(a1) : "v"(pq.w), "v"(h7));
    }
    return a0 + a1;
}

// rare fallback: degree > 64 (chunked, no-max softmax, fp32 sum)
// elc pre-offset to batch b; el value at slot k is elc[k*8]
__device__ __noinline__ float gat_big(const int* __restrict__ buck,
                                      const unsigned short* __restrict__ elc, int deg,
                                      const float* __restrict__ asrc,
                                      const char* __restrict__ hB,
                                      float adg, int lane, unsigned int cl2,
                                      unsigned short* pArr, unsigned int* oArr) {
    if (deg <= 0) return 0.f;
    float acc = 0.f, sum = 0.f;
    for (int k0 = 0; k0 < deg; k0 += 64) {
        int k = k0 + lane;
        bool v = k < deg;
        unsigned idx = v ? (unsigned)k : 0u;
        unsigned s = (unsigned)buck[idx];
        float el = __half2float(__ushort_as_half(elc[(size_t)idx * 8]));
        float lg = asrc[s] + adg + el;
        lg = fmaxf(lg, 0.2f * lg);
        float p = v ? __expf(lg) : 0.f;
        asm volatile("s_waitcnt lgkmcnt(0)" ::: "memory");
        pArr[lane] = __half_as_ushort(__float2half(p));
        oArr[lane] = s * HROW;
        sum += wave_sum(p);
        asm volatile("s_waitcnt lgkmcnt(0)" ::: "memory");
        int valid = (deg - k0) < 64 ? (deg - k0) : 64;
        unsigned int dummy = 0;
        acc += accum_f16(pArr, oArr, valid, hB, cl2, dummy);
    }
    return acc * __builtin_amdgcn_rcpf(sum + 1e-16f);
}

// ---------------- K2: fused gather, XCD-pinned by batch (b = blockIdx & 7) ----------------
__global__ __launch_bounds__(256, 8) void k2_gather(
        const int* __restrict__ bcnt, const int* __restrict__ bbuck,
        const unsigned short* __restrict__ elb16,
        const int* __restrict__ scnt, const int* __restrict__ sbuck,
        const unsigned short* __restrict__ els16,
        const unsigned short* __restrict__ h_b, const unsigned short* __restrict__ h_s,
        const float* __restrict__ asb, const float* __restrict__ adb,
        const float* __restrict__ ass, const float* __restrict__ ads,
        const float* __restrict__ bias_b, const float* __restrict__ bias_s,
        const float* __restrict__ P, float* __restrict__ out) {
    __shared__ __align__(16) unsigned short pLds[4][2][64];  // f16 p per edge slot
    __shared__ __align__(16) unsigned int   oLds[4][2][64];  // prescaled byte offsets
    int blk = blockIdx.x;
    int b = blk & 7;                               // XCD pin: round-robin blk->XCD
    int w = threadIdx.x >> 6;
    unsigned int g = (((unsigned)blk >> 3) << 2) + w;
    unsigned int lane = threadIdx.x & 63;
    unsigned int cl2 = (lane < CC ? lane : 0) * 2;

    int degb = bcnt[g];  degb = degb < BCAP ? degb : BCAP;
    unsigned int sct = g >> 9;            // NN = 2^9
    unsigned int n = g & (NN - 1);
    int degs = scnt[n];  degs = degs < SCAP ? degs : SCAP;

    const int* bb = bbuck + (size_t)g * BCAP;
    const unsigned short* elbp = elb16 + (size_t)g * BCAP * 8 + b;   // value at slot k: elbp[k*8]
    const int* sb = sbuck + (size_t)n * SCAP;
    const unsigned short* elsp = els16 + (size_t)n * SCAP * 8 + b;
    const float* asrcb = asb + (size_t)b * NG;
    const char* hbB = (const char*)(h_b + (size_t)b * NG * CC);
    size_t basebg = (size_t)b * NG + (size_t)sct * NN;
    const float* asrcs = ass + basebg;
    const char* hsB = (const char*)(h_s + basebg * CC);
    float adgb = adb[(size_t)b * NG + g];
    float adgs = ads[basebg + n];

    float vb, vs;
    if (degb <= 64 && degs <= 64) {
        bool vB = lane < (unsigned)degb, vS = lane < (unsigned)degs;
        unsigned slb = vB ? lane : 0u;
        unsigned sls = vS ? lane : 0u;
        unsigned srcb = (unsigned)bb[slb];           // coalesced 4B
        unsigned srcs = (unsigned)sb[sls];
        float elbv = __half2float(__ushort_as_half(elbp[slb * 8]));  // coalesced 2B, stride 16B
        float elsv = __half2float(__ushort_as_half(elsp[sls * 8]));
        float lgb = asrcb[srcb] + adgb + elbv;
        float lgs = asrcs[srcs] + adgs + elsv;
        lgb = fmaxf(lgb, 0.2f * lgb);                // leaky(0.2): max(x, 0.2x)
        lgs = fmaxf(lgs, 0.2f * lgs);
        float pb = vB ? __expf(lgb) : 0.f;           // logits bounded: no max-sub needed
        float ps = vS ? __expf(lgs) : 0.f;
        pLds[w][0][lane] = __half_as_ushort(__float2half(pb));
        pLds[w][1][lane] = __half_as_ushort(__float2half(ps));
        oLds[w][0][lane] = srcb * HROW;
        oLds[w][1][lane] = srcs * HROW;
        asm volatile("s_waitcnt lgkmcnt(0)" ::: "memory");
        unsigned int psumb = 0u, psums = 0u;
        u32x4 rb = make_rsrc(hbB);
        u32x4 rs = make_rsrc(hsB);
        float accb = accum_srsrc(&pLds[w][0][0], &oLds[w][0][0], degb, rb, cl2, psumb);
        float accs = accum_srsrc(&pLds[w][1][0], &oLds[w][1][0], degs, rs, cl2, psums);
        __half2 hb2 = __builtin_bit_cast(__half2, psumb);
        __half2 hs2 = __builtin_bit_cast(__half2, psums);
        float sumb = __low2float(hb2) + __high2float(hb2);
        float sums = __low2float(hs2) + __high2float(hs2);
        vb = accb * __builtin_amdgcn_rcpf(sumb + 1e-16f);
        vs = accs * __builtin_amdgcn_rcpf(sums + 1e-16f);
    } else {
        vb = gat_big(bb, elbp, degb, asrcb, hbB, adgb, lane, cl2,
                     &pLds[w][0][0], &oLds[w][0][0]);
        vs = gat_big(sb, elsp, degs, asrcs, hsB, adgs, lane, cl2,
                     &pLds[w][1][0], &oLds[w][1][0]);
    }

    if (lane < CC) {
        float ob = vb + bias_b[lane];
        ob = fmaxf(ob, 0.01f * ob);          // leaky(0.01)
        float os = vs + bias_s[lane];
        out[((size_t)b * NG + g) * CC + lane] = P[10] * ob + P[11] * os;
    }
}

extern "C" void kernel_launch(void* const* d_in, const int* in_sizes, int n_in,
                              void* d_out, int out_size, void* d_ws, size_t ws_size,
                              hipStream_t stream) {
    const float* x          = (const float*)d_in[0];
    const int*   bend_ei    = (const int*)d_in[1];
    const int*   sec_ei     = (const int*)d_in[2];
    const float* bend_attr  = (const float*)d_in[3];
    const float* sec_attr   = (const float*)d_in[4];
    const float* enc_W      = (const float*)d_in[5];
    const float* enc_b      = (const float*)d_in[6];
    const float* Wb         = (const float*)d_in[7];
    const float* a_src_b    = (const float*)d_in[8];
    const float* a_dst_b    = (const float*)d_in[9];
    const float* We_b       = (const float*)d_in[10];
    const float* a_e_b      = (const float*)d_in[11];
    const float* bias_b     = (const float*)d_in[12];
    const float* Ws         = (const float*)d_in[13];
    const float* a_src_s    = (const float*)d_in[14];
    const float* a_dst_s    = (const float*)d_in[15];
    const float* We_s       = (const float*)d_in[16];
    const float* a_e_s      = (const float*)d_in[17];
    const float* bias_s     = (const float*)d_in[18];
    const float* mix_w      = (const float*)d_in[19];
    float* out = (float*)d_out;

    char* base = (char*)d_ws;
    size_t off = 0;
    auto alloc = [&](size_t bytes) -> char* {
        off = (off + 255) & ~(size_t)255;
        char* p = base + off;
        off += bytes;
        return p;
    };
    float* P        = (float*)alloc(128 * sizeof(float));
    int* bcnt       = (int*)alloc((NG + NN) * sizeof(int));   // contiguous: one zero pass
    int* scnt       = bcnt + NG;
    int* bbuck      = (int*)alloc((size_t)NG * BCAP * sizeof(int));
    int* sbuck      = (int*)alloc((size_t)NN * SCAP * sizeof(int));
    uint4* elb16    = (uint4*)alloc((size_t)NG * BCAP * sizeof(uint4));  // [slot][8 f16]
    uint4* els16    = (uint4*)alloc((size_t)NN * SCAP * sizeof(uint4));
    unsigned short* h_b = (unsigned short*)alloc((size_t)BB * NG * CC * sizeof(unsigned short));
    unsigned short* h_s = (unsigned short*)alloc((size_t)BB * NG * CC * sizeof(unsigned short));
    float* asb      = (float*)alloc((size_t)BB * NG * sizeof(float));
    float* adb      = (float*)alloc((size_t)BB * NG * sizeof(float));
    float* ass      = (float*)alloc((size_t)BB * NG * sizeof(float));
    float* ads      = (float*)alloc((size_t)BB * NG * sizeof(float));
    (void)ws_size; (void)in_sizes; (void)n_in; (void)out_size;

    k0_init<<<(NG + NN + 255) / 256, 256, 0, stream>>>(enc_W, enc_b,
                                                       Wb, a_src_b, a_dst_b, We_b, a_e_b,
                                                       Ws, a_src_s, a_dst_s, We_s, a_e_s,
                                                       mix_w, P, bcnt);

    int k1_blocks = FEAT_NB + FILLB_NB + FILLS_NB;
    k1_all<<<k1_blocks, 256, 0, stream>>>(x, bend_ei, sec_ei, bend_attr, sec_attr,
                                          Wb, Ws, P, h_b, h_s, asb, adb, ass, ads,
                                          bcnt, bbuck, elb16, scnt, sbuck, els16);

    int k2_blocks = 8 * (NG / 4);   // b = blk & 7, 4 nodes per block
    k2_gather<<<k2_blocks, 256, 0, stream>>>(bcnt, bbuck, (const unsigned short*)elb16,
                                             scnt, sbuck, (const unsigned short*)els16,
                                             h_b, h_s, asb, adb, ass, ads,
                                             bias_b, bias_s, P, out);
}